// Round 7
// baseline (427.372 us; speedup 1.0000x reference)
//
#include <hip/hip_runtime.h>

#define E_TOTAL 600000
#define N_NODES 50000
#define NETILES 9375        // 600000 / 64 exact, no tail
#define NNT 782             // ceil(50000/64) node tiles
#define LDS_X 136           // node-kernel x-stage row stride (shorts), 272B
#define LDP 264             // pack/hidden row stride (shorts), 528B

typedef __attribute__((ext_vector_type(8))) short short8;
typedef __attribute__((ext_vector_type(8))) _Float16 half8;
typedef __attribute__((ext_vector_type(4))) float f32x4;

__device__ __forceinline__ unsigned f2bf_u(float f) {
  union { float f; unsigned u; } v; v.f = f;
  return (v.u + 0x7fffu + ((v.u >> 16) & 1u)) >> 16;  // RNE
}
__device__ __forceinline__ unsigned short f2h_u(float f) {
  union { _Float16 h; unsigned short u; } v; v.h = (_Float16)f;
  return v.u;
}

// ---- prep: W1c/W2t2/b1h as before; blocks 81+ zero the sort histogram ----
__global__ __launch_bounds__(256) void prep(
    const float* __restrict__ W1, const float* __restrict__ W2,
    const float* __restrict__ b1,
    unsigned short* __restrict__ W1c, unsigned short* __restrict__ W2t2,
    unsigned short* __restrict__ b1h, int* __restrict__ hist) {
  __shared__ float t[32][33];
  int bid = blockIdx.x;
  int tx = threadIdx.x & 31, ty = threadIdx.x >> 5;
  if (bid < 64) {
    int k0 = (bid >> 3) * 32, n0 = (bid & 7) * 32;
#pragma unroll
    for (int i = 0; i < 32; i += 8) t[ty + i][tx] = W1[(k0 + ty + i) * 256 + n0 + tx];
    __syncthreads();
    int coff = (k0 >= 128) ? 256 : 0;
#pragma unroll
    for (int i = 0; i < 32; i += 8)
      W1c[(n0 + ty + i + coff) * 128 + (k0 & 127) + tx] = (unsigned short)f2bf_u(t[tx][ty + i]);
  } else if (bid < 80) {
    int b = bid - 64;
    int k0 = (b >> 1) * 32, n0 = (b & 1) * 32;
#pragma unroll
    for (int i = 0; i < 32; i += 8) t[ty + i][tx] = W2[(k0 + ty + i) * 64 + n0 + tx];
    __syncthreads();
#pragma unroll
    for (int i = 0; i < 32; i += 8)
      W2t2[(n0 + ty + i) * 256 + k0 + tx] = f2h_u(t[tx][ty + i]);
  } else if (bid == 80) {
    b1h[threadIdx.x] = f2h_u(b1[threadIdx.x]);
  } else {
    int i = (bid - 81) * 256 + threadIdx.x;
    if (i < N_NODES) hist[i] = 0;
  }
}

// ---- sort pass 1: histogram of src ----
__global__ __launch_bounds__(256) void ehist(const int* __restrict__ ei, int* __restrict__ hist) {
  int e = blockIdx.x * 256 + threadIdx.x;
  if (e < E_TOTAL) atomicAdd(&hist[ei[e]], 1);
}

// ---- sort pass 2: single-block exclusive scan over 50000 counters ----
__global__ __launch_bounds__(256) void escan(const int* __restrict__ hist, int* __restrict__ offs) {
  __shared__ int tmp[256];
  const int t = threadIdx.x;
  const int b = t * 196;                  // 196*256 = 50176 >= 50000
  int s = 0;
#pragma unroll 4
  for (int i = 0; i < 196; ++i) { int idx = b + i; if (idx < N_NODES) s += hist[idx]; }
  tmp[t] = s; __syncthreads();
  for (int o = 1; o < 256; o <<= 1) {
    int v = (t >= o) ? tmp[t - o] : 0;
    __syncthreads();
    tmp[t] += v;
    __syncthreads();
  }
  int run = tmp[t] - s;                   // exclusive
  for (int i = 0; i < 196; ++i) {
    int idx = b + i;
    if (idx < N_NODES) { offs[idx] = run; run += hist[idx]; }
  }
}

// ---- sort pass 3: scatter (ss,sd,se) ordered by src; order within a src run
// is atomic-nondeterministic but results are order-independent ----
__global__ __launch_bounds__(256) void escatter(const int* __restrict__ ei, int* __restrict__ offs,
                                                int* __restrict__ ss, int* __restrict__ sd,
                                                int* __restrict__ se) {
  int e = blockIdx.x * 256 + threadIdx.x;
  if (e < E_TOTAL) {
    int s = ei[e], d = ei[E_TOTAL + e];
    int p = atomicAdd(&offs[s], 1);
    ss[p] = s; sd[p] = d; se[p] = e;
  }
}

// ---- node kernel: U[n][256] = x@W1[:128]; V[n][256] = x@W1[128:] (f16, split tables) ----
__global__ __launch_bounds__(256, 3) void node_uv(
    const float* __restrict__ x, const unsigned short* __restrict__ W1c,
    unsigned short* __restrict__ U, unsigned short* __restrict__ V) {
  __shared__ __align__(16) unsigned short xt[64 * LDP];
  const int tid = threadIdx.x;
  const int ntile = (int)blockIdx.x >> 1, chalf = blockIdx.x & 1;
  const int n0 = ntile * 64;
  const int lane = tid & 63, w = tid >> 6, m = lane & 15, q = lane >> 4;

  const int kb = (tid & 15) * 8;
  const int r0 = tid >> 4;
#pragma unroll
  for (int i = 0; i < 4; ++i) {
    int r = r0 + 16 * i;
    int n = n0 + r; if (n >= N_NODES) n = N_NODES - 1;
    const float* p = x + (size_t)n * 128 + kb;
    f32x4 g0 = *(const f32x4*)p, g1 = *(const f32x4*)(p + 4);
    short8 s;
#pragma unroll
    for (int j = 0; j < 4; ++j) { s[j] = (short)f2bf_u(g0[j]); s[4 + j] = (short)f2bf_u(g1[j]); }
    *(short8*)&xt[r * LDS_X + kb] = s;
  }

  int w1o[4];
#pragma unroll
  for (int nt = 0; nt < 4; ++nt) w1o[nt] = (chalf * 256 + (w * 4 + nt) * 16 + m) * 128 + q * 8;
  short8 wa[2][4];
#pragma unroll
  for (int nt = 0; nt < 4; ++nt) wa[0][nt] = *(const short8*)&W1c[w1o[nt]];

  __syncthreads();

  f32x4 acc[4][4];
#pragma unroll
  for (int nt = 0; nt < 4; ++nt)
#pragma unroll
    for (int mt = 0; mt < 4; ++mt) acc[nt][mt] = (f32x4){0.f, 0.f, 0.f, 0.f};

#pragma unroll
  for (int kk = 0; kk < 4; ++kk) {
    const int cur = kk & 1, nx = cur ^ 1;
    if (kk < 3) {
#pragma unroll
      for (int nt = 0; nt < 4; ++nt) wa[nx][nt] = *(const short8*)&W1c[w1o[nt] + (kk + 1) * 32];
    }
    short8 f[4];
#pragma unroll
    for (int mt = 0; mt < 4; ++mt)
      f[mt] = *(const short8*)&xt[(mt * 16 + m) * LDS_X + kk * 32 + q * 8];
#pragma unroll
    for (int nt = 0; nt < 4; ++nt)
#pragma unroll
      for (int mt = 0; mt < 4; ++mt)
        acc[nt][mt] = __builtin_amdgcn_mfma_f32_16x16x32_bf16(wa[cur][nt], f[mt], acc[nt][mt], 0, 0, 0);
  }

  __syncthreads();

#pragma unroll
  for (int nt = 0; nt < 4; ++nt)
#pragma unroll
    for (int mt = 0; mt < 4; ++mt) {
      union { _Float16 h[4]; uint2 u; } pk;
#pragma unroll
      for (int r = 0; r < 4; ++r) pk.h[r] = (_Float16)acc[nt][mt][r];
      *(uint2*)&xt[(mt * 16 + m) * LDP + (w * 4 + nt) * 16 + q * 4] = pk.u;
    }

  __syncthreads();

  const int rr = tid >> 2, c8 = tid & 3;
  if (n0 + rr < N_NODES) {
    unsigned short* dst = (chalf ? V : U) + (size_t)(n0 + rr) * 256;
#pragma unroll
    for (int i = 0; i < 8; ++i) {
      int ch = c8 + 4 * i;
      *(short8*)&dst[ch * 8] = *(const short8*)&xt[rr * LDP + ch * 8];
    }
  }
}

// ---- edge kernel: sorted-by-src tiles. u-gather is L1/L2-sequential (~6 distinct
// rows/tile); v-gather random; out scattered by original edge id ----
__global__ __launch_bounds__(256, 4) void edge_mlp(
    const unsigned short* __restrict__ U, const unsigned short* __restrict__ V,
    const int* __restrict__ ss, const int* __restrict__ sd, const int* __restrict__ se,
    const unsigned short* __restrict__ W2t2, const unsigned short* __restrict__ b1h,
    const float* __restrict__ b2, float* __restrict__ out) {
  __shared__ __align__(16) unsigned short hid[64 * LDP];
  const int tid = threadIdx.x;
  const int base = blockIdx.x * 64;
  const int lane = tid & 63, w = tid >> 6, m = lane & 15, q = lane >> 4;
  const int c = tid & 31;    // 16B chunk (k-dims c*8..c*8+8)
  const int e0 = tid >> 5;   // 0..7

  half8 w2r[8];
  const int w2off = (w * 16 + m) * 256 + q * 8;
#pragma unroll
  for (int kk = 0; kk < 8; ++kk) w2r[kk] = *(const half8*)&W2t2[w2off + kk * 32];
  half8 bias = *(const half8*)&b1h[c * 8];
  f32x4 b2v = *(const f32x4*)&b2[w * 16 + q * 4];

  int si[8], di[8];
#pragma unroll
  for (int i = 0; i < 8; ++i) {
    int r = base + e0 + 8 * i;
    si[i] = ss[r];
    di[i] = sd[r];
  }

#pragma unroll
  for (int g = 0; g < 2; ++g) {
    half8 lu[4], lv[4];
#pragma unroll
    for (int i = 0; i < 4; ++i) {
      const int r = g * 4 + i;
      lu[i] = *(const half8*)&U[(size_t)si[r] * 256 + c * 8];
      lv[i] = *(const half8*)&V[(size_t)di[r] * 256 + c * 8];
    }
#pragma unroll
    for (int i = 0; i < 4; ++i) {
      const int r = g * 4 + i;
      half8 s = lu[i] + lv[i] + bias;   // v_pk_add_f16 x8
#pragma unroll
      for (int j = 0; j < 8; ++j) s[j] = s[j] > (_Float16)0 ? s[j] : (_Float16)0;
      *(half8*)&hid[(e0 + 8 * r) * LDP + c * 8] = s;
    }
  }

  __syncthreads();

  f32x4 acc2[4];
#pragma unroll
  for (int mt = 0; mt < 4; ++mt) acc2[mt] = (f32x4){0.f, 0.f, 0.f, 0.f};
#pragma unroll
  for (int kk = 0; kk < 8; ++kk) {
#pragma unroll
    for (int mt = 0; mt < 4; ++mt) {
      half8 h = *(const half8*)&hid[(mt * 16 + m) * LDP + kk * 32 + q * 8];
      acc2[mt] = __builtin_amdgcn_mfma_f32_16x16x32_f16(w2r[kk], h, acc2[mt], 0, 0, 0);
    }
  }

#pragma unroll
  for (int mt = 0; mt < 4; ++mt) {
    int eo = se[base + mt * 16 + m];    // original edge id (L1-hot, 16-int segment)
    f32x4 o;
#pragma unroll
    for (int r = 0; r < 4; ++r) o[r] = acc2[mt][r] + b2v[r];
    __builtin_nontemporal_store(o, (f32x4*)&out[(size_t)eo * 64 + w * 16 + q * 4]);
  }
}

extern "C" void kernel_launch(void* const* d_in, const int* in_sizes, int n_in,
                              void* d_out, int out_size, void* d_ws, size_t ws_size,
                              hipStream_t stream) {
  const float* x  = (const float*)d_in[0];
  const int*   ei = (const int*)d_in[1];
  const float* W1 = (const float*)d_in[2];
  const float* b1 = (const float*)d_in[3];
  const float* W2 = (const float*)d_in[4];
  const float* b2 = (const float*)d_in[5];
  float* out = (float*)d_out;

  unsigned short* W1c  = (unsigned short*)d_ws;      // [512][128] bf16
  unsigned short* W2t2 = W1c + 512 * 128;            // [64][256] f16
  unsigned short* b1h  = W2t2 + 64 * 256;            // [256] f16
  unsigned short* U    = b1h + 256;                  // [50000][256] f16 (25.6 MB)
  unsigned short* V    = U + (size_t)N_NODES * 256;  // [50000][256] f16 (25.6 MB)
  int* hist = (int*)(V + (size_t)N_NODES * 256);     // [50000]
  int* offs = hist + N_NODES;                        // [50000]
  int* ss   = offs + N_NODES;                        // [600000]
  int* sd   = ss + E_TOTAL;                          // [600000]
  int* se   = sd + E_TOTAL;                          // [600000]

  prep<<<277, 256, 0, stream>>>(W1, W2, b1, W1c, W2t2, b1h, hist);
  ehist<<<2344, 256, 0, stream>>>(ei, hist);
  escan<<<1, 256, 0, stream>>>(hist, offs);
  escatter<<<2344, 256, 0, stream>>>(ei, offs, ss, sd, se);
  node_uv<<<NNT * 2, 256, 0, stream>>>(x, W1c, U, V);
  edge_mlp<<<NETILES, 256, 0, stream>>>(U, V, ss, sd, se, W2t2, b1h, b2, out);
}

// Round 8
// 334.864 us; speedup vs baseline: 1.2763x; 1.2763x over previous
//
#include <hip/hip_runtime.h>

#define E_TOTAL 600000
#define N_NODES 50000
#define NETILES 9375        // 600000 / 64 exact, no tail
#define NNT 782             // ceil(50000/64) node tiles
#define SCAN_B 196          // scan chunks: 196*256 = 50176 >= 50000
#define LDS_X 136           // node-kernel x-stage row stride (shorts), 272B
#define LDP 264             // pack/hidden row stride (shorts), 528B

typedef __attribute__((ext_vector_type(8))) short short8;
typedef __attribute__((ext_vector_type(8))) _Float16 half8;
typedef __attribute__((ext_vector_type(4))) float f32x4;

__device__ __forceinline__ unsigned f2bf_u(float f) {
  union { float f; unsigned u; } v; v.f = f;
  return (v.u + 0x7fffu + ((v.u >> 16) & 1u)) >> 16;  // RNE
}
__device__ __forceinline__ unsigned short f2h_u(float f) {
  union { _Float16 h; unsigned short u; } v; v.h = (_Float16)f;
  return v.u;
}

// ---- prep: W1c/W2t2/b1h; blocks 81+ zero the sort histogram ----
__global__ __launch_bounds__(256) void prep(
    const float* __restrict__ W1, const float* __restrict__ W2,
    const float* __restrict__ b1,
    unsigned short* __restrict__ W1c, unsigned short* __restrict__ W2t2,
    unsigned short* __restrict__ b1h, int* __restrict__ hist) {
  __shared__ float t[32][33];
  int bid = blockIdx.x;
  int tx = threadIdx.x & 31, ty = threadIdx.x >> 5;
  if (bid < 64) {
    int k0 = (bid >> 3) * 32, n0 = (bid & 7) * 32;
#pragma unroll
    for (int i = 0; i < 32; i += 8) t[ty + i][tx] = W1[(k0 + ty + i) * 256 + n0 + tx];
    __syncthreads();
    int coff = (k0 >= 128) ? 256 : 0;
#pragma unroll
    for (int i = 0; i < 32; i += 8)
      W1c[(n0 + ty + i + coff) * 128 + (k0 & 127) + tx] = (unsigned short)f2bf_u(t[tx][ty + i]);
  } else if (bid < 80) {
    int b = bid - 64;
    int k0 = (b >> 1) * 32, n0 = (b & 1) * 32;
#pragma unroll
    for (int i = 0; i < 32; i += 8) t[ty + i][tx] = W2[(k0 + ty + i) * 64 + n0 + tx];
    __syncthreads();
#pragma unroll
    for (int i = 0; i < 32; i += 8)
      W2t2[(n0 + ty + i) * 256 + k0 + tx] = f2h_u(t[tx][ty + i]);
  } else if (bid == 80) {
    b1h[threadIdx.x] = f2h_u(b1[threadIdx.x]);
  } else {
    int i = (bid - 81) * 256 + threadIdx.x;
    if (i < N_NODES) hist[i] = 0;
  }
}

// ---- sort pass 1: histogram of src ----
__global__ __launch_bounds__(256) void ehist(const int* __restrict__ ei, int* __restrict__ hist) {
  int e = blockIdx.x * 256 + threadIdx.x;
  if (e < E_TOTAL) atomicAdd(&hist[ei[e]], 1);
}

// ---- parallel scan, phase 1: per-256-chunk exclusive scan + chunk total ----
__global__ __launch_bounds__(256) void escan_local(const int* __restrict__ hist,
                                                   int* __restrict__ offs,
                                                   int* __restrict__ bsum) {
  __shared__ int tmp[256];
  const int b = blockIdx.x, t = threadIdx.x;
  const int i = b * 256 + t;
  int v = (i < N_NODES) ? hist[i] : 0;
  tmp[t] = v;
  __syncthreads();
  for (int o = 1; o < 256; o <<= 1) {
    int u = (t >= o) ? tmp[t - o] : 0;
    __syncthreads();
    tmp[t] += u;
    __syncthreads();
  }
  if (i < N_NODES) offs[i] = tmp[t] - v;   // exclusive within chunk
  if (t == 255) bsum[b] = tmp[255];        // chunk total
}

// ---- phase 2: single-block exclusive scan of the 196 chunk totals ----
__global__ __launch_bounds__(256) void escan_block(const int* __restrict__ bsum,
                                                   int* __restrict__ boff) {
  __shared__ int tmp[256];
  const int t = threadIdx.x;
  int v = (t < SCAN_B) ? bsum[t] : 0;
  tmp[t] = v;
  __syncthreads();
  for (int o = 1; o < 256; o <<= 1) {
    int u = (t >= o) ? tmp[t - o] : 0;
    __syncthreads();
    tmp[t] += u;
    __syncthreads();
  }
  if (t < SCAN_B) boff[t] = tmp[t] - v;    // exclusive
}

// ---- phase 3: add chunk offsets ----
__global__ __launch_bounds__(256) void escan_add(int* __restrict__ offs,
                                                 const int* __restrict__ boff) {
  const int i = blockIdx.x * 256 + threadIdx.x;
  if (i < N_NODES) offs[i] += boff[blockIdx.x];
}

// ---- sort pass 3: scatter (ss,sd,se) ordered by src; order within a src run
// is atomic-nondeterministic but results are order-independent ----
__global__ __launch_bounds__(256) void escatter(const int* __restrict__ ei, int* __restrict__ offs,
                                                int* __restrict__ ss, int* __restrict__ sd,
                                                int* __restrict__ se) {
  int e = blockIdx.x * 256 + threadIdx.x;
  if (e < E_TOTAL) {
    int s = ei[e], d = ei[E_TOTAL + e];
    int p = atomicAdd(&offs[s], 1);
    ss[p] = s; sd[p] = d; se[p] = e;
  }
}

// ---- node kernel: U[n][256] = x@W1[:128]; V[n][256] = x@W1[128:] (f16, split tables) ----
__global__ __launch_bounds__(256, 3) void node_uv(
    const float* __restrict__ x, const unsigned short* __restrict__ W1c,
    unsigned short* __restrict__ U, unsigned short* __restrict__ V) {
  __shared__ __align__(16) unsigned short xt[64 * LDP];
  const int tid = threadIdx.x;
  const int ntile = (int)blockIdx.x >> 1, chalf = blockIdx.x & 1;
  const int n0 = ntile * 64;
  const int lane = tid & 63, w = tid >> 6, m = lane & 15, q = lane >> 4;

  const int kb = (tid & 15) * 8;
  const int r0 = tid >> 4;
#pragma unroll
  for (int i = 0; i < 4; ++i) {
    int r = r0 + 16 * i;
    int n = n0 + r; if (n >= N_NODES) n = N_NODES - 1;
    const float* p = x + (size_t)n * 128 + kb;
    f32x4 g0 = *(const f32x4*)p, g1 = *(const f32x4*)(p + 4);
    short8 s;
#pragma unroll
    for (int j = 0; j < 4; ++j) { s[j] = (short)f2bf_u(g0[j]); s[4 + j] = (short)f2bf_u(g1[j]); }
    *(short8*)&xt[r * LDS_X + kb] = s;
  }

  int w1o[4];
#pragma unroll
  for (int nt = 0; nt < 4; ++nt) w1o[nt] = (chalf * 256 + (w * 4 + nt) * 16 + m) * 128 + q * 8;
  short8 wa[2][4];
#pragma unroll
  for (int nt = 0; nt < 4; ++nt) wa[0][nt] = *(const short8*)&W1c[w1o[nt]];

  __syncthreads();

  f32x4 acc[4][4];
#pragma unroll
  for (int nt = 0; nt < 4; ++nt)
#pragma unroll
    for (int mt = 0; mt < 4; ++mt) acc[nt][mt] = (f32x4){0.f, 0.f, 0.f, 0.f};

#pragma unroll
  for (int kk = 0; kk < 4; ++kk) {
    const int cur = kk & 1, nx = cur ^ 1;
    if (kk < 3) {
#pragma unroll
      for (int nt = 0; nt < 4; ++nt) wa[nx][nt] = *(const short8*)&W1c[w1o[nt] + (kk + 1) * 32];
    }
    short8 f[4];
#pragma unroll
    for (int mt = 0; mt < 4; ++mt)
      f[mt] = *(const short8*)&xt[(mt * 16 + m) * LDS_X + kk * 32 + q * 8];
#pragma unroll
    for (int nt = 0; nt < 4; ++nt)
#pragma unroll
      for (int mt = 0; mt < 4; ++mt)
        acc[nt][mt] = __builtin_amdgcn_mfma_f32_16x16x32_bf16(wa[cur][nt], f[mt], acc[nt][mt], 0, 0, 0);
  }

  __syncthreads();

#pragma unroll
  for (int nt = 0; nt < 4; ++nt)
#pragma unroll
    for (int mt = 0; mt < 4; ++mt) {
      union { _Float16 h[4]; uint2 u; } pk;
#pragma unroll
      for (int r = 0; r < 4; ++r) pk.h[r] = (_Float16)acc[nt][mt][r];
      *(uint2*)&xt[(mt * 16 + m) * LDP + (w * 4 + nt) * 16 + q * 4] = pk.u;
    }

  __syncthreads();

  const int rr = tid >> 2, c8 = tid & 3;
  if (n0 + rr < N_NODES) {
    unsigned short* dst = (chalf ? V : U) + (size_t)(n0 + rr) * 256;
#pragma unroll
    for (int i = 0; i < 8; ++i) {
      int ch = c8 + 4 * i;
      *(short8*)&dst[ch * 8] = *(const short8*)&xt[rr * LDP + ch * 8];
    }
  }
}

// ---- edge kernel: sorted-by-src tiles. u-gather L1/L2-sequential; v random;
// out scattered by original edge id (full 256B rows) ----
__global__ __launch_bounds__(256, 4) void edge_mlp(
    const unsigned short* __restrict__ U, const unsigned short* __restrict__ V,
    const int* __restrict__ ss, const int* __restrict__ sd, const int* __restrict__ se,
    const unsigned short* __restrict__ W2t2, const unsigned short* __restrict__ b1h,
    const float* __restrict__ b2, float* __restrict__ out) {
  __shared__ __align__(16) unsigned short hid[64 * LDP];
  const int tid = threadIdx.x;
  const int base = blockIdx.x * 64;
  const int lane = tid & 63, w = tid >> 6, m = lane & 15, q = lane >> 4;
  const int c = tid & 31;    // 16B chunk (k-dims c*8..c*8+8)
  const int e0 = tid >> 5;   // 0..7

  half8 w2r[8];
  const int w2off = (w * 16 + m) * 256 + q * 8;
#pragma unroll
  for (int kk = 0; kk < 8; ++kk) w2r[kk] = *(const half8*)&W2t2[w2off + kk * 32];
  half8 bias = *(const half8*)&b1h[c * 8];
  f32x4 b2v = *(const f32x4*)&b2[w * 16 + q * 4];

  int si[8], di[8];
#pragma unroll
  for (int i = 0; i < 8; ++i) {
    int r = base + e0 + 8 * i;
    si[i] = ss[r];
    di[i] = sd[r];
  }

#pragma unroll
  for (int g = 0; g < 2; ++g) {
    half8 lu[4], lv[4];
#pragma unroll
    for (int i = 0; i < 4; ++i) {
      const int r = g * 4 + i;
      lu[i] = *(const half8*)&U[(size_t)si[r] * 256 + c * 8];
      lv[i] = *(const half8*)&V[(size_t)di[r] * 256 + c * 8];
    }
#pragma unroll
    for (int i = 0; i < 4; ++i) {
      const int r = g * 4 + i;
      half8 s = lu[i] + lv[i] + bias;   // v_pk_add_f16 x8
#pragma unroll
      for (int j = 0; j < 8; ++j) s[j] = s[j] > (_Float16)0 ? s[j] : (_Float16)0;
      *(half8*)&hid[(e0 + 8 * r) * LDP + c * 8] = s;
    }
  }

  __syncthreads();

  f32x4 acc2[4];
#pragma unroll
  for (int mt = 0; mt < 4; ++mt) acc2[mt] = (f32x4){0.f, 0.f, 0.f, 0.f};
#pragma unroll
  for (int kk = 0; kk < 8; ++kk) {
#pragma unroll
    for (int mt = 0; mt < 4; ++mt) {
      half8 h = *(const half8*)&hid[(mt * 16 + m) * LDP + kk * 32 + q * 8];
      acc2[mt] = __builtin_amdgcn_mfma_f32_16x16x32_f16(w2r[kk], h, acc2[mt], 0, 0, 0);
    }
  }

#pragma unroll
  for (int mt = 0; mt < 4; ++mt) {
    int eo = se[base + mt * 16 + m];    // original edge id (L1-hot segment)
    f32x4 o;
#pragma unroll
    for (int r = 0; r < 4; ++r) o[r] = acc2[mt][r] + b2v[r];
    __builtin_nontemporal_store(o, (f32x4*)&out[(size_t)eo * 64 + w * 16 + q * 4]);
  }
}

extern "C" void kernel_launch(void* const* d_in, const int* in_sizes, int n_in,
                              void* d_out, int out_size, void* d_ws, size_t ws_size,
                              hipStream_t stream) {
  const float* x  = (const float*)d_in[0];
  const int*   ei = (const int*)d_in[1];
  const float* W1 = (const float*)d_in[2];
  const float* b1 = (const float*)d_in[3];
  const float* W2 = (const float*)d_in[4];
  const float* b2 = (const float*)d_in[5];
  float* out = (float*)d_out;

  unsigned short* W1c  = (unsigned short*)d_ws;      // [512][128] bf16
  unsigned short* W2t2 = W1c + 512 * 128;            // [64][256] f16
  unsigned short* b1h  = W2t2 + 64 * 256;            // [256] f16
  unsigned short* U    = b1h + 256;                  // [50000][256] f16 (25.6 MB)
  unsigned short* V    = U + (size_t)N_NODES * 256;  // [50000][256] f16 (25.6 MB)
  int* hist = (int*)(V + (size_t)N_NODES * 256);     // [50000]
  int* offs = hist + N_NODES;                        // [50000]
  int* ss   = offs + N_NODES;                        // [600000]
  int* sd   = ss + E_TOTAL;                          // [600000]
  int* se   = sd + E_TOTAL;                          // [600000]
  int* bsum = se + E_TOTAL;                          // [196]
  int* boff = bsum + SCAN_B;                         // [196]

  prep<<<277, 256, 0, stream>>>(W1, W2, b1, W1c, W2t2, b1h, hist);
  ehist<<<2344, 256, 0, stream>>>(ei, hist);
  escan_local<<<SCAN_B, 256, 0, stream>>>(hist, offs, bsum);
  escan_block<<<1, 256, 0, stream>>>(bsum, boff);
  escan_add<<<SCAN_B, 256, 0, stream>>>(offs, boff);
  escatter<<<2344, 256, 0, stream>>>(ei, offs, ss, sd, se);
  node_uv<<<NNT * 2, 256, 0, stream>>>(x, W1c, U, V);
  edge_mlp<<<NETILES, 256, 0, stream>>>(U, V, ss, sd, se, W2t2, b1h, b2, out);
}